// Round 3
// baseline (941.060 us; speedup 1.0000x reference)
//
#include <hip/hip_runtime.h>
#include <hip/hip_bf16.h>
#include <stdint.h>

#define D_DIM 1024
#define NH 16
#define DHD 64
#define SEQ 64
#define NBATCH 256
#define M_TOT 16384            // NBATCH*SEQ
#define ATT_SCALE 0.125f       // 64^-0.5
#define LN_EPS 1e-5f

// 256^2 8-phase GEMM geometry
#define BM 256
#define BN 256
#define BKT 64
#define NTK (D_DIM / BKT)      // 16 K-tiles

typedef __attribute__((ext_vector_type(8))) short bf16x8;
typedef __attribute__((ext_vector_type(4))) float f32x4;

__device__ __forceinline__ float bf2f(short s) {
  union { uint32_t u; float f; } c;
  c.u = ((uint32_t)(uint16_t)s) << 16;
  return c.f;
}

__device__ __forceinline__ short f2bf(float f) {
  union { __hip_bfloat16 h; short s; } c; c.h = __float2bfloat16(f);
  return c.s;
}

__device__ __forceinline__ bf16x8 cvt8(float4 a, float4 b) {
  bf16x8 r;
  r[0] = f2bf(a.x); r[1] = f2bf(a.y); r[2] = f2bf(a.z); r[3] = f2bf(a.w);
  r[4] = f2bf(b.x); r[5] = f2bf(b.y); r[6] = f2bf(b.z); r[7] = f2bf(b.w);
  return r;
}

// async global->LDS, 16B/lane. LDS dest = wave-uniform base + lane*16.
__device__ __forceinline__ void cp16(const void* g, void* l) {
  __builtin_amdgcn_global_load_lds(
      (const __attribute__((address_space(1))) uint32_t*)g,
      (__attribute__((address_space(3))) uint32_t*)l, 16, 0, 0);
}

// ---------------------------------------------------------------------------
// Kernel 0: fp32 -> bf16 conversion for all weights (stacked Wall) + hidden.
// ---------------------------------------------------------------------------
__global__ void conv_all(const float* __restrict__ Wq, const float* __restrict__ Wk,
                         const float* __restrict__ Wv, const float* __restrict__ Wo,
                         const float* __restrict__ H,
                         __hip_bfloat16* __restrict__ Wall,
                         __hip_bfloat16* __restrict__ Hb) {
  const size_t idx8 = ((size_t)blockIdx.x * 256 + threadIdx.x) * 8;
  const size_t WE = (size_t)4 * D_DIM * D_DIM;   // 4,194,304
  const float* src;
  __hip_bfloat16* dst;
  if (idx8 < WE) {
    int z = (int)(idx8 >> 20);
    size_t off = idx8 & ((1u << 20) - 1);
    src = ((z == 0) ? Wq : (z == 1) ? Wk : (z == 2) ? Wv : Wo) + off;
    dst = Wall + idx8;
  } else {
    size_t off = idx8 - WE;
    src = H + off;
    dst = Hb + off;
  }
  float4 a = ((const float4*)src)[0];
  float4 b = ((const float4*)src)[1];
  *(bf16x8*)(short*)dst = cvt8(a, b);
}

// ---------------------------------------------------------------------------
// 256x256 4-phase/K-tile pipelined GEMM core, 2-K-tile-deep prefetch.
// 8 waves (2x4), BK=64, LDS 128 KiB double-buffered.
// During GEMM_TILE(J, CUR, NXT) we read CUR (tile j) and stage ALL 8 loads of
// tile j+2 back into CUR, each region immediately after its last read:
//   P2 stages A-Q0,A-Q2 (rows 0-63/128-191; last read P1)
//   P3 stages B-Q0..Q3   (last read P2)
//   P4 stages A-Q1,A-Q3  (rows 64-127/192-255; last read P3)
// Tile j+1 (in NXT) was fully staged during tile j-1. The single counted
// vmcnt(8) at P4 drains tile j+1's 8 loads (issued 4-7 phases back, well past
// HBM latency) and leaves tile j+2's 8 in flight. Never vmcnt(0) mid-loop.
// Region safety: each staged region had {lgkmcnt(0) + barrier} between its
// last ds_read and the stage issue. P4 needs no extra pre-MFMA barrier (its
// MFMAs are register-only; end-P3 barrier orders the Q1/Q3 stage).
// LDS swizzle: physical chunk = logical chunk ^ (row&7), applied on ds_read
// addr AND pre-applied to the global source column (both-sides-or-neither).
// ---------------------------------------------------------------------------
#define GEMM_TILE(J, CUR, NXT) do {                                           \
    /* phase 1: ds A rows0-63 (8) + B cols0-31 (4); no staging */             \
    _Pragma("unroll") for (int i_ = 0; i_ < 4; ++i_) {                        \
      af[i_][0] = *(const bf16x8*)(LdsA[CUR] + aoff + i_ * 2048 + colsw0);    \
      af[i_][1] = *(const bf16x8*)(LdsA[CUR] + aoff + i_ * 2048 + colsw1);    \
    }                                                                         \
    _Pragma("unroll") for (int q_ = 0; q_ < 2; ++q_) {                        \
      bfr[q_][0] = *(const bf16x8*)(LdsB[CUR] + boff + q_ * 2048 + colsw0);   \
      bfr[q_][1] = *(const bf16x8*)(LdsB[CUR] + boff + q_ * 2048 + colsw1);   \
    }                                                                         \
    __builtin_amdgcn_s_barrier();                                             \
    __asm volatile("s_waitcnt lgkmcnt(0)" ::: "memory");                      \
    __builtin_amdgcn_s_setprio(1);                                            \
    _Pragma("unroll") for (int i_ = 0; i_ < 4; ++i_)                          \
      _Pragma("unroll") for (int q_ = 0; q_ < 2; ++q_) {                      \
        acc[i_][q_] = __builtin_amdgcn_mfma_f32_16x16x32_bf16(                \
            af[i_][0], bfr[q_][0], acc[i_][q_], 0, 0, 0);                     \
        acc[i_][q_] = __builtin_amdgcn_mfma_f32_16x16x32_bf16(                \
            af[i_][1], bfr[q_][1], acc[i_][q_], 0, 0, 0);                     \
      }                                                                       \
    __builtin_amdgcn_s_setprio(0);                                            \
    __builtin_amdgcn_s_barrier();                                             \
    /* phase 2: ds B cols32-63 (4); stage tile j+2 A-Q0, A-Q2 -> CUR */       \
    _Pragma("unroll") for (int q_ = 0; q_ < 2; ++q_) {                        \
      bfr[2 + q_][0] =                                                        \
          *(const bf16x8*)(LdsB[CUR] + boff + (2 + q_) * 2048 + colsw0);      \
      bfr[2 + q_][1] =                                                        \
          *(const bf16x8*)(LdsB[CUR] + boff + (2 + q_) * 2048 + colsw1);      \
    }                                                                         \
    if ((J) + 2 < NTK) { STG_A(CUR, (J) + 2, 0); STG_A(CUR, (J) + 2, 2); }    \
    __builtin_amdgcn_s_barrier();                                             \
    __asm volatile("s_waitcnt lgkmcnt(0)" ::: "memory");                      \
    __builtin_amdgcn_s_setprio(1);                                            \
    _Pragma("unroll") for (int i_ = 0; i_ < 4; ++i_)                          \
      _Pragma("unroll") for (int q_ = 0; q_ < 2; ++q_) {                      \
        acc[i_][2 + q_] = __builtin_amdgcn_mfma_f32_16x16x32_bf16(            \
            af[i_][0], bfr[2 + q_][0], acc[i_][2 + q_], 0, 0, 0);             \
        acc[i_][2 + q_] = __builtin_amdgcn_mfma_f32_16x16x32_bf16(            \
            af[i_][1], bfr[2 + q_][1], acc[i_][2 + q_], 0, 0, 0);             \
      }                                                                       \
    __builtin_amdgcn_s_setprio(0);                                            \
    __builtin_amdgcn_s_barrier();                                             \
    /* phase 3: ds A rows64-127 (8); stage tile j+2 B-Q0..Q3 -> CUR */        \
    _Pragma("unroll") for (int i_ = 0; i_ < 4; ++i_) {                        \
      af[i_][0] =                                                             \
          *(const bf16x8*)(LdsA[CUR] + aoff + 8192 + i_ * 2048 + colsw0);     \
      af[i_][1] =                                                             \
          *(const bf16x8*)(LdsA[CUR] + aoff + 8192 + i_ * 2048 + colsw1);     \
    }                                                                         \
    if ((J) + 2 < NTK) {                                                      \
      STG_B(CUR, (J) + 2, 0); STG_B(CUR, (J) + 2, 1);                         \
      STG_B(CUR, (J) + 2, 2); STG_B(CUR, (J) + 2, 3);                         \
    }                                                                         \
    __builtin_amdgcn_s_barrier();                                             \
    __asm volatile("s_waitcnt lgkmcnt(0)" ::: "memory");                      \
    __builtin_amdgcn_s_setprio(1);                                            \
    _Pragma("unroll") for (int i_ = 0; i_ < 4; ++i_)                          \
      _Pragma("unroll") for (int q_ = 0; q_ < 2; ++q_) {                      \
        acc[4 + i_][2 + q_] = __builtin_amdgcn_mfma_f32_16x16x32_bf16(        \
            af[i_][0], bfr[2 + q_][0], acc[4 + i_][2 + q_], 0, 0, 0);         \
        acc[4 + i_][2 + q_] = __builtin_amdgcn_mfma_f32_16x16x32_bf16(        \
            af[i_][1], bfr[2 + q_][1], acc[4 + i_][2 + q_], 0, 0, 0);         \
      }                                                                       \
    __builtin_amdgcn_s_setprio(0);                                            \
    __builtin_amdgcn_s_barrier();                                             \
    /* phase 4: stage tile j+2 A-Q1, A-Q3 -> CUR; MFMA; counted vmcnt */      \
    if ((J) + 2 < NTK) { STG_A(CUR, (J) + 2, 1); STG_A(CUR, (J) + 2, 3); }    \
    __builtin_amdgcn_s_setprio(1);                                            \
    _Pragma("unroll") for (int i_ = 0; i_ < 4; ++i_)                          \
      _Pragma("unroll") for (int q_ = 0; q_ < 2; ++q_) {                      \
        acc[4 + i_][q_] = __builtin_amdgcn_mfma_f32_16x16x32_bf16(            \
            af[i_][0], bfr[q_][0], acc[4 + i_][q_], 0, 0, 0);                 \
        acc[4 + i_][q_] = __builtin_amdgcn_mfma_f32_16x16x32_bf16(            \
            af[i_][1], bfr[q_][1], acc[4 + i_][q_], 0, 0, 0);                 \
      }                                                                       \
    __builtin_amdgcn_s_setprio(0);                                            \
    if ((J) + 2 < NTK) {                                                      \
      __asm volatile("s_waitcnt vmcnt(8)" ::: "memory");                      \
    } else if ((J) + 1 < NTK) {                                               \
      __asm volatile("s_waitcnt vmcnt(0)" ::: "memory");                      \
    }                                                                         \
    __builtin_amdgcn_s_barrier();                                             \
  } while (0)

#define GEMM_PIPELINE() do {                                                  \
    /* prologue: full stage of tile0 -> buf0 AND tile1 -> buf1 */             \
    STG_A(0, 0, 0); STG_A(0, 0, 1); STG_A(0, 0, 2); STG_A(0, 0, 3);           \
    STG_B(0, 0, 0); STG_B(0, 0, 1); STG_B(0, 0, 2); STG_B(0, 0, 3);           \
    STG_A(1, 1, 0); STG_A(1, 1, 1); STG_A(1, 1, 2); STG_A(1, 1, 3);           \
    STG_B(1, 1, 0); STG_B(1, 1, 1); STG_B(1, 1, 2); STG_B(1, 1, 3);           \
    __asm volatile("s_waitcnt vmcnt(8)" ::: "memory");                        \
    __builtin_amdgcn_s_barrier();                                             \
    _Pragma("unroll 1") for (int it_ = 0; it_ < NTK / 2; ++it_) {             \
      GEMM_TILE(2 * it_, 0, 1);                                               \
      GEMM_TILE(2 * it_ + 1, 1, 0);                                           \
    }                                                                         \
  } while (0)

// ---------------------------------------------------------------------------
// Kernel 1: merged QKV GEMM. One block per (m0,n0); z-loop inside so the
// A-panel (512 KB) is fetched through L3 once and is L2-hot for z=1,2.
// Grid (64,4) = 256 blocks = one clean round on 256 CUs.
// z<2 -> out [B,H,seq,dh]; z==2 -> out [B,H,dh,seq] (V transposed).
// ---------------------------------------------------------------------------
__global__ void __launch_bounds__(512, 2)
gemm_qkv_bf(const __hip_bfloat16* __restrict__ Hb,
            const __hip_bfloat16* __restrict__ Wall,
            __hip_bfloat16* __restrict__ Qw,
            __hip_bfloat16* __restrict__ Kw,
            __hip_bfloat16* __restrict__ Vtw) {
  __shared__ __align__(16) char LdsA[2][BM * BKT * 2];   // 2 x 32 KiB
  __shared__ __align__(16) char LdsB[2][BN * BKT * 2];   // 2 x 32 KiB
  const int tid = threadIdx.x;
  const int lane = tid & 63, wave = tid >> 6;
  const int l16 = lane & 15, kq = lane >> 4;
  const int wr = wave >> 2, wc = wave & 3;               // 2 x 4 wave grid
  const int m0 = blockIdx.x * BM, n0 = blockIdx.y * BN;
  const int wub = wave * 1024;                           // wave-uniform LDS base
  const int srow = tid >> 3;                             // staging row in quarter
  const int scol8 = (((tid >> 3) & 7) ^ (tid & 7)) << 3; // pre-swizzled src col
  const size_t a_thr = (size_t)(m0 + srow) * D_DIM + scol8;
  const size_t b_thr = (size_t)(n0 + srow) * D_DIM + scol8;
  // ds_read physical col offsets: logical ^ ((row&7)<<4); row&7 == l16&7
  const int colsw0 = (kq * 16) ^ ((l16 & 7) << 4);
  const int colsw1 = (64 + kq * 16) ^ ((l16 & 7) << 4);
  const int aoff = (wr * 128 + l16) * 128;
  const int boff = (wc * 64 + l16) * 128;

#define STG_A(BUF, JT, Q)                                                      \
  cp16(Hb + a_thr + (size_t)(Q) * (64 * D_DIM) + (JT) * BKT,                   \
       LdsA[BUF] + (Q) * 8192 + wub)
#define STG_B(BUF, JT, Q)                                                      \
  cp16(Bm + b_thr + (size_t)(Q) * (64 * D_DIM) + (JT) * BKT,                   \
       LdsB[BUF] + (Q) * 8192 + wub)

#pragma unroll 1
  for (int z = 0; z < 3; ++z) {
    const __hip_bfloat16* Bm = Wall + (size_t)z * D_DIM * D_DIM;
    f32x4 acc[8][4] = {};
    bf16x8 af[4][2], bfr[4][2];

    GEMM_PIPELINE();

    __hip_bfloat16* outp = (z == 0) ? Qw : (z == 1) ? Kw : Vtw;
    const int zlt2 = (z < 2);
#pragma unroll
    for (int i = 0; i < 8; ++i) {
#pragma unroll
      for (int r = 0; r < 4; ++r) {
        int gm = m0 + wr * 128 + i * 16 + kq * 4 + r;
        int b = gm >> 6, ks = gm & 63;
#pragma unroll
        for (int jf = 0; jf < 4; ++jf) {
          int gn = n0 + wc * 64 + jf * 16 + l16;
          int h = gn >> 6, dh = gn & 63;
          size_t idx = zlt2 ? ((size_t)(b * NH + h) * SEQ + ks) * DHD + dh
                            : ((size_t)(b * NH + h) * DHD + dh) * SEQ + ks;
          outp[idx] = __float2bfloat16(acc[i][jf][r]);
        }
      }
    }
  }

#undef STG_A
#undef STG_B
}

// ---------------------------------------------------------------------------
// Kernel 2: attention, one head per wave (unchanged, round-5 proven).
// ---------------------------------------------------------------------------
__global__ void attn_v2(__hip_bfloat16* Qw,                 // in: Q, out: O (aliased)
                        const __hip_bfloat16* __restrict__ Kw,
                        const __hip_bfloat16* __restrict__ Vtw,
                        const int* __restrict__ mask) {
  __shared__ __align__(16) __hip_bfloat16 Ps[4][16 * 72];   // 9216 B total
  const int tid = threadIdx.x;
  const int lane = tid & 63;
  const int wave = tid >> 6;
  const int l16 = lane & 15, kq = lane >> 4;                // kq = quad 0..3
  const int hh = blockIdx.x * 4 + wave;                     // head id 0..4095
  const int b = hh >> 4;
  const size_t base = (size_t)hh * 4096;                    // 64x64 slice
  __hip_bfloat16* Pw = &Ps[wave][0];

  bf16x8 kf[2][4], vf[2][4], qf[4][2];
#pragma unroll
  for (int kk2 = 0; kk2 < 2; ++kk2)
#pragma unroll
    for (int j = 0; j < 4; ++j) {
      kf[kk2][j] = *(const bf16x8*)(Kw + base + (j * 16 + l16) * 64 + kk2 * 32 + kq * 8);
      vf[kk2][j] = *(const bf16x8*)(Vtw + base + (j * 16 + l16) * 64 + kk2 * 32 + kq * 8);
    }
#pragma unroll
  for (int qt = 0; qt < 4; ++qt)
#pragma unroll
    for (int kk2 = 0; kk2 < 2; ++kk2)
      qf[qt][kk2] = *(const bf16x8*)(Qw + base + (qt * 16 + l16) * 64 + kk2 * 32 + kq * 8);

#pragma unroll
  for (int qt = 0; qt < 4; ++qt) {
    f32x4 accS[4] = {};
#pragma unroll
    for (int kk2 = 0; kk2 < 2; ++kk2)
#pragma unroll
      for (int j = 0; j < 4; ++j)
        accS[j] = __builtin_amdgcn_mfma_f32_16x16x32_bf16(qf[qt][kk2], kf[kk2][j],
                                                          accS[j], 0, 0, 0);
#pragma unroll
    for (int r = 0; r < 4; ++r) {
      float sv[4];
      float m = -1e30f;
#pragma unroll
      for (int j = 0; j < 4; ++j) { sv[j] = accS[j][r] * ATT_SCALE; m = fmaxf(m, sv[j]); }
#pragma unroll
      for (int off = 1; off < 16; off <<= 1) m = fmaxf(m, __shfl_xor(m, off, 64));
      float s = 0.f;
#pragma unroll
      for (int j = 0; j < 4; ++j) { sv[j] = __expf(sv[j] - m); s += sv[j]; }
#pragma unroll
      for (int off = 1; off < 16; off <<= 1) s += __shfl_xor(s, off, 64);
      float inv = 1.0f / s;
      int ql = kq * 4 + r;
#pragma unroll
      for (int j = 0; j < 4; ++j)
        Pw[ql * 72 + j * 16 + l16] = __float2bfloat16(sv[j] * inv);
    }
    __asm volatile("s_waitcnt lgkmcnt(0)" ::: "memory");

    f32x4 accO[4] = {};
#pragma unroll
    for (int kk2 = 0; kk2 < 2; ++kk2) {
      bf16x8 a = *(const bf16x8*)((const short*)Pw + l16 * 72 + kk2 * 32 + kq * 8);
#pragma unroll
      for (int j = 0; j < 4; ++j)
        accO[j] = __builtin_amdgcn_mfma_f32_16x16x32_bf16(a, vf[kk2][j], accO[j], 0, 0, 0);
    }
    __asm volatile("s_waitcnt lgkmcnt(0)" ::: "memory");

#pragma unroll
    for (int r = 0; r < 4; ++r) {
      int q = qt * 16 + kq * 4 + r;
      float mk = mask[b * SEQ + q] ? 1.0f : 0.0f;
#pragma unroll
      for (int j = 0; j < 4; ++j)
        Qw[base + q * DHD + j * 16 + l16] = __float2bfloat16(accO[j][r] * mk);
    }
  }
}

// ---------------------------------------------------------------------------
// Kernel 3: O projection + gated residual, same pipelined core.
// Hb(bf16) updated IN-PLACE: Hb = Hb + mask[m]*(O @ Wo^T).
// ---------------------------------------------------------------------------
__global__ void __launch_bounds__(512, 2)
gemm_o(const __hip_bfloat16* __restrict__ Ow,   // [B,H,seq,dh]
       const __hip_bfloat16* __restrict__ WoB,  // bf16 [1024][1024]
       const int* __restrict__ mask,
       __hip_bfloat16* Hb) {                    // residual in/out
  __shared__ __align__(16) char LdsA[2][BM * BKT * 2];
  __shared__ __align__(16) char LdsB[2][BN * BKT * 2];
  const int tid = threadIdx.x;
  const int lane = tid & 63, wave = tid >> 6;
  const int l16 = lane & 15, kq = lane >> 4;
  const int wr = wave >> 2, wc = wave & 3;
  const int m0 = blockIdx.x * BM, n0 = blockIdx.y * BN;
  const int wub = wave * 1024;
  const int srow = tid >> 3;
  const int scol8 = (((tid >> 3) & 7) ^ (tid & 7)) << 3;
  // A source: token t = m0 + q*64 + srow -> b = (m0>>6)+q, s = srow;
  // col f = jt*64 + scol8 -> h = jt, dh = scol8 (BKT == DHD == 64).
  const size_t ao_thr = ((size_t)(m0 >> 6) << 16) + (srow << 6) + scol8;
  const size_t b_thr = (size_t)(n0 + srow) * D_DIM + scol8;
  const int colsw0 = (kq * 16) ^ ((l16 & 7) << 4);
  const int colsw1 = (64 + kq * 16) ^ ((l16 & 7) << 4);
  const int aoff = (wr * 128 + l16) * 128;
  const int boff = (wc * 64 + l16) * 128;

  f32x4 acc[8][4] = {};
  bf16x8 af[4][2], bfr[4][2];

#define STG_A(BUF, JT, Q)                                                      \
  cp16(Ow + ao_thr + ((size_t)(Q) << 16) + ((size_t)(JT) << 12),               \
       LdsA[BUF] + (Q) * 8192 + wub)
#define STG_B(BUF, JT, Q)                                                      \
  cp16(WoB + b_thr + (size_t)(Q) * (64 * D_DIM) + (JT) * BKT,                  \
       LdsB[BUF] + (Q) * 8192 + wub)

  GEMM_PIPELINE();

#undef STG_A
#undef STG_B

#pragma unroll
  for (int i = 0; i < 8; ++i) {
#pragma unroll
    for (int r = 0; r < 4; ++r) {
      int gm = m0 + wr * 128 + i * 16 + kq * 4 + r;
      float mk = mask[gm] ? 1.0f : 0.0f;
#pragma unroll
      for (int jf = 0; jf < 4; ++jf) {
        int gn = n0 + wc * 64 + jf * 16 + l16;
        size_t idx = (size_t)gm * D_DIM + gn;
        Hb[idx] = __float2bfloat16(__bfloat162float(Hb[idx]) + mk * acc[i][jf][r]);
      }
    }
  }
}

// ---------------------------------------------------------------------------
// Kernel 4: LayerNorm over D=1024, bf16 in / fp32 out (unchanged).
// ---------------------------------------------------------------------------
__global__ void ln_bf(const __hip_bfloat16* __restrict__ Hf,
                      const float* __restrict__ gamma,
                      const float* __restrict__ beta,
                      float* __restrict__ out) {
  __shared__ float red[4];
  const int row = blockIdx.x, tid = threadIdx.x;
  const int wave = tid >> 6, lane = tid & 63;
  const size_t boff = (size_t)row * D_DIM + tid * 8;

  bf16x8 v = *(const bf16x8*)((const short*)Hf + boff);
  float f[8], s = 0.f, ss = 0.f;
#pragma unroll
  for (int k = 0; k < 8; ++k) { f[k] = bf2f(v[k]); s += f[k]; ss += f[k] * f[k]; }
#pragma unroll
  for (int off = 1; off < 64; off <<= 1) {
    s += __shfl_xor(s, off, 64);
    ss += __shfl_xor(ss, off, 64);
  }
  if (lane == 0) { red[wave * 2] = s; red[wave * 2 + 1] = ss; }
  __syncthreads();
  s = red[0] + red[2];
  ss = red[1] + red[3];
  const float mu = s * (1.0f / D_DIM);
  const float var = ss * (1.0f / D_DIM) - mu * mu;
  const float rs = rsqrtf(var + LN_EPS);

  float4 g0 = ((const float4*)(gamma + tid * 8))[0];
  float4 g1 = ((const float4*)(gamma + tid * 8))[1];
  float4 b0 = ((const float4*)(beta + tid * 8))[0];
  float4 b1 = ((const float4*)(beta + tid * 8))[1];
  float g[8] = {g0.x, g0.y, g0.z, g0.w, g1.x, g1.y, g1.z, g1.w};
  float bb[8] = {b0.x, b0.y, b0.z, b0.w, b1.x, b1.y, b1.z, b1.w};
  float o[8];
#pragma unroll
  for (int k = 0; k < 8; ++k)
    o[k] = (f[k] - mu) * rs * g[k] + bb[k];
  ((float4*)(out + boff))[0] = make_float4(o[0], o[1], o[2], o[3]);
  ((float4*)(out + boff))[1] = make_float4(o[4], o[5], o[6], o[7]);
}

// ---------------------------------------------------------------------------
extern "C" void kernel_launch(void* const* d_in, const int* in_sizes, int n_in,
                              void* d_out, int out_size, void* d_ws, size_t ws_size,
                              hipStream_t stream) {
  const float* hidden = (const float*)d_in[0];
  const int* mask = (const int*)d_in[1];
  const float* Wq = (const float*)d_in[2];
  const float* Wk = (const float*)d_in[3];
  const float* Wv = (const float*)d_in[4];
  const float* Wo = (const float*)d_in[5];
  const float* gamma = (const float*)d_in[6];
  const float* beta = (const float*)d_in[7];
  float* out = (float*)d_out;

  const size_t SZ = (size_t)M_TOT * D_DIM;        // 16,777,216 elements
  __hip_bfloat16* Hb   = (__hip_bfloat16*)d_ws;   // bf16 hidden; in-place residual
  __hip_bfloat16* Kw   = Hb + SZ;
  __hip_bfloat16* Qw   = Hb + 2 * SZ;             // O written in-place by attn
  __hip_bfloat16* Vtw  = Hb + 3 * SZ;
  __hip_bfloat16* Wall = Hb + 4 * SZ;             // bf16 [4][1024][1024]

  conv_all<<<dim3(10240), 256, 0, stream>>>(Wq, Wk, Wv, Wo, hidden, Wall, Hb);
  gemm_qkv_bf<<<dim3(64, 4), 512, 0, stream>>>(Hb, Wall, Qw, Kw, Vtw);
  attn_v2<<<dim3(1024), 256, 0, stream>>>(Qw, Kw, Vtw, mask);
  gemm_o<<<dim3(64, 4), 512, 0, stream>>>(Qw, Wall + 3 * D_DIM * D_DIM, mask, Hb);
  ln_bf<<<dim3(16384), 128, 0, stream>>>(Hb, gamma, beta, out);
}

// Round 4
// 336.700 us; speedup vs baseline: 2.7949x; 2.7949x over previous
//
#include <hip/hip_runtime.h>
#include <hip/hip_bf16.h>
#include <stdint.h>

#define D_DIM 1024
#define NH 16
#define DHD 64
#define SEQ 64
#define NBATCH 256
#define M_TOT 16384            // NBATCH*SEQ
#define ATT_SCALE 0.125f       // 64^-0.5
#define LN_EPS 1e-5f

// 256^2 GEMM geometry
#define BM 256
#define BN 256
#define BKT 64
#define NTK (D_DIM / BKT)      // 16 K-tiles

typedef __attribute__((ext_vector_type(8))) short bf16x8;
typedef __attribute__((ext_vector_type(4))) float f32x4;

__device__ __forceinline__ float bf2f(short s) {
  union { uint32_t u; float f; } c;
  c.u = ((uint32_t)(uint16_t)s) << 16;
  return c.f;
}

__device__ __forceinline__ short f2bf(float f) {
  union { __hip_bfloat16 h; short s; } c; c.h = __float2bfloat16(f);
  return c.s;
}

__device__ __forceinline__ bf16x8 cvt8(float4 a, float4 b) {
  bf16x8 r;
  r[0] = f2bf(a.x); r[1] = f2bf(a.y); r[2] = f2bf(a.z); r[3] = f2bf(a.w);
  r[4] = f2bf(b.x); r[5] = f2bf(b.y); r[6] = f2bf(b.z); r[7] = f2bf(b.w);
  return r;
}

// async global->LDS, 16B/lane. LDS dest = wave-uniform base + lane*16.
__device__ __forceinline__ void cp16(const void* g, void* l) {
  __builtin_amdgcn_global_load_lds(
      (const __attribute__((address_space(1))) uint32_t*)g,
      (__attribute__((address_space(3))) uint32_t*)l, 16, 0, 0);
}

// ---------------------------------------------------------------------------
// Kernel 0: fp32 -> bf16 conversion for all weights (stacked Wall) + hidden.
// ---------------------------------------------------------------------------
__global__ void conv_all(const float* __restrict__ Wq, const float* __restrict__ Wk,
                         const float* __restrict__ Wv, const float* __restrict__ Wo,
                         const float* __restrict__ H,
                         __hip_bfloat16* __restrict__ Wall,
                         __hip_bfloat16* __restrict__ Hb) {
  const size_t idx8 = ((size_t)blockIdx.x * 256 + threadIdx.x) * 8;
  const size_t WE = (size_t)4 * D_DIM * D_DIM;   // 4,194,304
  const float* src;
  __hip_bfloat16* dst;
  if (idx8 < WE) {
    int z = (int)(idx8 >> 20);
    size_t off = idx8 & ((1u << 20) - 1);
    src = ((z == 0) ? Wq : (z == 1) ? Wk : (z == 2) ? Wv : Wo) + off;
    dst = Wall + idx8;
  } else {
    size_t off = idx8 - WE;
    src = H + off;
    dst = Hb + off;
  }
  float4 a = ((const float4*)src)[0];
  float4 b = ((const float4*)src)[1];
  *(bf16x8*)(short*)dst = cvt8(a, b);
}

// ---------------------------------------------------------------------------
// 256x256 4-phase/K-tile pipelined GEMM core, 2-K-tile-deep prefetch.
// 8 waves (2x4), BK=64, LDS 128 KiB double-buffered.
// During GEMM_TILE(J, CUR, NXT) we read CUR (tile j) and stage ALL 8 loads of
// tile j+2 back into CUR, each region immediately after its last read:
//   P2 stages A-Q0,A-Q2 (rows 0-63/128-191; last read P1)
//   P3 stages B-Q0..Q3   (last read P2)
//   P4 stages A-Q1,A-Q3  (rows 64-127/192-255; last read P3)
// Tile j+1 (in NXT) was fully staged during tile j-1. The single counted
// vmcnt(8) at P4 drains tile j+1's 8 loads (issued 4-7 phases back, well past
// HBM latency) and leaves tile j+2's 8 in flight. Never vmcnt(0) mid-loop.
// Region safety: each staged region had {lgkmcnt(0) + barrier} between its
// last ds_read and the stage issue. P4 needs no extra pre-MFMA barrier (its
// MFMAs are register-only; end-P3 barrier orders the Q1/Q3 stage).
// LDS swizzle: physical chunk = logical chunk ^ (row&7), applied on ds_read
// addr AND pre-applied to the global source column (both-sides-or-neither).
// NOTE (R3 lesson): this macro must NOT be wrapped in a runtime loop inside
// one kernel — doing so spilled the 128-VGPR accumulator to scratch
// (FETCH/WRITE exploded 10x). Keep one pipeline per kernel invocation.
// ---------------------------------------------------------------------------
#define GEMM_TILE(J, CUR, NXT) do {                                           \
    /* phase 1: ds A rows0-63 (8) + B cols0-31 (4); no staging */             \
    _Pragma("unroll") for (int i_ = 0; i_ < 4; ++i_) {                        \
      af[i_][0] = *(const bf16x8*)(LdsA[CUR] + aoff + i_ * 2048 + colsw0);    \
      af[i_][1] = *(const bf16x8*)(LdsA[CUR] + aoff + i_ * 2048 + colsw1);    \
    }                                                                         \
    _Pragma("unroll") for (int q_ = 0; q_ < 2; ++q_) {                        \
      bfr[q_][0] = *(const bf16x8*)(LdsB[CUR] + boff + q_ * 2048 + colsw0);   \
      bfr[q_][1] = *(const bf16x8*)(LdsB[CUR] + boff + q_ * 2048 + colsw1);   \
    }                                                                         \
    __builtin_amdgcn_s_barrier();                                             \
    __asm volatile("s_waitcnt lgkmcnt(0)" ::: "memory");                      \
    __builtin_amdgcn_s_setprio(1);                                            \
    _Pragma("unroll") for (int i_ = 0; i_ < 4; ++i_)                          \
      _Pragma("unroll") for (int q_ = 0; q_ < 2; ++q_) {                      \
        acc[i_][q_] = __builtin_amdgcn_mfma_f32_16x16x32_bf16(                \
            af[i_][0], bfr[q_][0], acc[i_][q_], 0, 0, 0);                     \
        acc[i_][q_] = __builtin_amdgcn_mfma_f32_16x16x32_bf16(                \
            af[i_][1], bfr[q_][1], acc[i_][q_], 0, 0, 0);                     \
      }                                                                       \
    __builtin_amdgcn_s_setprio(0);                                            \
    __builtin_amdgcn_s_barrier();                                             \
    /* phase 2: ds B cols32-63 (4); stage tile j+2 A-Q0, A-Q2 -> CUR */       \
    _Pragma("unroll") for (int q_ = 0; q_ < 2; ++q_) {                        \
      bfr[2 + q_][0] =                                                        \
          *(const bf16x8*)(LdsB[CUR] + boff + (2 + q_) * 2048 + colsw0);      \
      bfr[2 + q_][1] =                                                        \
          *(const bf16x8*)(LdsB[CUR] + boff + (2 + q_) * 2048 + colsw1);      \
    }                                                                         \
    if ((J) + 2 < NTK) { STG_A(CUR, (J) + 2, 0); STG_A(CUR, (J) + 2, 2); }    \
    __builtin_amdgcn_s_barrier();                                             \
    __asm volatile("s_waitcnt lgkmcnt(0)" ::: "memory");                      \
    __builtin_amdgcn_s_setprio(1);                                            \
    _Pragma("unroll") for (int i_ = 0; i_ < 4; ++i_)                          \
      _Pragma("unroll") for (int q_ = 0; q_ < 2; ++q_) {                      \
        acc[i_][2 + q_] = __builtin_amdgcn_mfma_f32_16x16x32_bf16(            \
            af[i_][0], bfr[2 + q_][0], acc[i_][2 + q_], 0, 0, 0);             \
        acc[i_][2 + q_] = __builtin_amdgcn_mfma_f32_16x16x32_bf16(            \
            af[i_][1], bfr[2 + q_][1], acc[i_][2 + q_], 0, 0, 0);             \
      }                                                                       \
    __builtin_amdgcn_s_setprio(0);                                            \
    __builtin_amdgcn_s_barrier();                                             \
    /* phase 3: ds A rows64-127 (8); stage tile j+2 B-Q0..Q3 -> CUR */        \
    _Pragma("unroll") for (int i_ = 0; i_ < 4; ++i_) {                        \
      af[i_][0] =                                                             \
          *(const bf16x8*)(LdsA[CUR] + aoff + 8192 + i_ * 2048 + colsw0);     \
      af[i_][1] =                                                             \
          *(const bf16x8*)(LdsA[CUR] + aoff + 8192 + i_ * 2048 + colsw1);     \
    }                                                                         \
    if ((J) + 2 < NTK) {                                                      \
      STG_B(CUR, (J) + 2, 0); STG_B(CUR, (J) + 2, 1);                         \
      STG_B(CUR, (J) + 2, 2); STG_B(CUR, (J) + 2, 3);                         \
    }                                                                         \
    __builtin_amdgcn_s_barrier();                                             \
    __asm volatile("s_waitcnt lgkmcnt(0)" ::: "memory");                      \
    __builtin_amdgcn_s_setprio(1);                                            \
    _Pragma("unroll") for (int i_ = 0; i_ < 4; ++i_)                          \
      _Pragma("unroll") for (int q_ = 0; q_ < 2; ++q_) {                      \
        acc[4 + i_][2 + q_] = __builtin_amdgcn_mfma_f32_16x16x32_bf16(        \
            af[i_][0], bfr[2 + q_][0], acc[4 + i_][2 + q_], 0, 0, 0);         \
        acc[4 + i_][2 + q_] = __builtin_amdgcn_mfma_f32_16x16x32_bf16(        \
            af[i_][1], bfr[2 + q_][1], acc[4 + i_][2 + q_], 0, 0, 0);         \
      }                                                                       \
    __builtin_amdgcn_s_setprio(0);                                            \
    __builtin_amdgcn_s_barrier();                                             \
    /* phase 4: stage tile j+2 A-Q1, A-Q3 -> CUR; MFMA; counted vmcnt */      \
    if ((J) + 2 < NTK) { STG_A(CUR, (J) + 2, 1); STG_A(CUR, (J) + 2, 3); }    \
    __builtin_amdgcn_s_setprio(1);                                            \
    _Pragma("unroll") for (int i_ = 0; i_ < 4; ++i_)                          \
      _Pragma("unroll") for (int q_ = 0; q_ < 2; ++q_) {                      \
        acc[4 + i_][q_] = __builtin_amdgcn_mfma_f32_16x16x32_bf16(            \
            af[i_][0], bfr[q_][0], acc[4 + i_][q_], 0, 0, 0);                 \
        acc[4 + i_][q_] = __builtin_amdgcn_mfma_f32_16x16x32_bf16(            \
            af[i_][1], bfr[q_][1], acc[4 + i_][q_], 0, 0, 0);                 \
      }                                                                       \
    __builtin_amdgcn_s_setprio(0);                                            \
    if ((J) + 2 < NTK) {                                                      \
      __asm volatile("s_waitcnt vmcnt(8)" ::: "memory");                      \
    } else if ((J) + 1 < NTK) {                                               \
      __asm volatile("s_waitcnt vmcnt(0)" ::: "memory");                      \
    }                                                                         \
    __builtin_amdgcn_s_barrier();                                             \
  } while (0)

#define GEMM_PIPELINE() do {                                                  \
    /* prologue: full stage of tile0 -> buf0 AND tile1 -> buf1 */             \
    STG_A(0, 0, 0); STG_A(0, 0, 1); STG_A(0, 0, 2); STG_A(0, 0, 3);           \
    STG_B(0, 0, 0); STG_B(0, 0, 1); STG_B(0, 0, 2); STG_B(0, 0, 3);           \
    STG_A(1, 1, 0); STG_A(1, 1, 1); STG_A(1, 1, 2); STG_A(1, 1, 3);           \
    STG_B(1, 1, 0); STG_B(1, 1, 1); STG_B(1, 1, 2); STG_B(1, 1, 3);           \
    __asm volatile("s_waitcnt vmcnt(8)" ::: "memory");                        \
    __builtin_amdgcn_s_barrier();                                             \
    _Pragma("unroll 1") for (int it_ = 0; it_ < NTK / 2; ++it_) {             \
      GEMM_TILE(2 * it_, 0, 1);                                               \
      GEMM_TILE(2 * it_ + 1, 1, 0);                                           \
    }                                                                         \
  } while (0)

// ---------------------------------------------------------------------------
// Kernel 1: QKV GEMM. C[m,n] = sum_k A[m,k]*W[n,k]. 256x256 tile, 512 thr.
// Grid (64,4,3): one z per blockIdx.z (R3 lesson: z-loop inside the kernel
// spills the accumulator). z<2 -> out [B,H,seq,dh]; z==2 -> [B,H,dh,seq].
// ---------------------------------------------------------------------------
__global__ void __launch_bounds__(512, 2)
gemm_qkv_bf(const __hip_bfloat16* __restrict__ Hb,
            const __hip_bfloat16* __restrict__ Wall,
            __hip_bfloat16* __restrict__ Qw,
            __hip_bfloat16* __restrict__ Kw,
            __hip_bfloat16* __restrict__ Vtw) {
  __shared__ __align__(16) char LdsA[2][BM * BKT * 2];   // 2 x 32 KiB
  __shared__ __align__(16) char LdsB[2][BN * BKT * 2];   // 2 x 32 KiB
  const int tid = threadIdx.x;
  const int lane = tid & 63, wave = tid >> 6;
  const int l16 = lane & 15, kq = lane >> 4;
  const int wr = wave >> 2, wc = wave & 3;               // 2 x 4 wave grid
  const int m0 = blockIdx.x * BM, n0 = blockIdx.y * BN;
  const __hip_bfloat16* Bm = Wall + (size_t)blockIdx.z * D_DIM * D_DIM;
  const int wub = wave * 1024;                           // wave-uniform LDS base
  const int srow = tid >> 3;                             // staging row in quarter
  const int scol8 = (((tid >> 3) & 7) ^ (tid & 7)) << 3; // pre-swizzled src col
  const size_t a_thr = (size_t)(m0 + srow) * D_DIM + scol8;
  const size_t b_thr = (size_t)(n0 + srow) * D_DIM + scol8;
  // ds_read physical col offsets: logical ^ ((row&7)<<4); row&7 == l16&7
  const int colsw0 = (kq * 16) ^ ((l16 & 7) << 4);
  const int colsw1 = (64 + kq * 16) ^ ((l16 & 7) << 4);
  const int aoff = (wr * 128 + l16) * 128;
  const int boff = (wc * 64 + l16) * 128;

  f32x4 acc[8][4] = {};
  bf16x8 af[4][2], bfr[4][2];

#define STG_A(BUF, JT, Q)                                                      \
  cp16(Hb + a_thr + (size_t)(Q) * (64 * D_DIM) + (JT) * BKT,                   \
       LdsA[BUF] + (Q) * 8192 + wub)
#define STG_B(BUF, JT, Q)                                                      \
  cp16(Bm + b_thr + (size_t)(Q) * (64 * D_DIM) + (JT) * BKT,                   \
       LdsB[BUF] + (Q) * 8192 + wub)

  GEMM_PIPELINE();

#undef STG_A
#undef STG_B

  __hip_bfloat16* outp = (blockIdx.z == 0) ? Qw : (blockIdx.z == 1) ? Kw : Vtw;
  const int zlt2 = (blockIdx.z < 2);
#pragma unroll
  for (int i = 0; i < 8; ++i) {
#pragma unroll
    for (int r = 0; r < 4; ++r) {
      int gm = m0 + wr * 128 + i * 16 + kq * 4 + r;
      int b = gm >> 6, ks = gm & 63;
#pragma unroll
      for (int jf = 0; jf < 4; ++jf) {
        int gn = n0 + wc * 64 + jf * 16 + l16;
        int h = gn >> 6, dh = gn & 63;
        size_t idx = zlt2 ? ((size_t)(b * NH + h) * SEQ + ks) * DHD + dh
                          : ((size_t)(b * NH + h) * DHD + dh) * SEQ + ks;
        outp[idx] = __float2bfloat16(acc[i][jf][r]);
      }
    }
  }
}

// ---------------------------------------------------------------------------
// Kernel 2: attention, one head per wave (unchanged, round-5 proven).
// ---------------------------------------------------------------------------
__global__ void attn_v2(__hip_bfloat16* Qw,                 // in: Q, out: O (aliased)
                        const __hip_bfloat16* __restrict__ Kw,
                        const __hip_bfloat16* __restrict__ Vtw,
                        const int* __restrict__ mask) {
  __shared__ __align__(16) __hip_bfloat16 Ps[4][16 * 72];   // 9216 B total
  const int tid = threadIdx.x;
  const int lane = tid & 63;
  const int wave = tid >> 6;
  const int l16 = lane & 15, kq = lane >> 4;                // kq = quad 0..3
  const int hh = blockIdx.x * 4 + wave;                     // head id 0..4095
  const int b = hh >> 4;
  const size_t base = (size_t)hh * 4096;                    // 64x64 slice
  __hip_bfloat16* Pw = &Ps[wave][0];

  bf16x8 kf[2][4], vf[2][4], qf[4][2];
#pragma unroll
  for (int kk2 = 0; kk2 < 2; ++kk2)
#pragma unroll
    for (int j = 0; j < 4; ++j) {
      kf[kk2][j] = *(const bf16x8*)(Kw + base + (j * 16 + l16) * 64 + kk2 * 32 + kq * 8);
      vf[kk2][j] = *(const bf16x8*)(Vtw + base + (j * 16 + l16) * 64 + kk2 * 32 + kq * 8);
    }
#pragma unroll
  for (int qt = 0; qt < 4; ++qt)
#pragma unroll
    for (int kk2 = 0; kk2 < 2; ++kk2)
      qf[qt][kk2] = *(const bf16x8*)(Qw + base + (qt * 16 + l16) * 64 + kk2 * 32 + kq * 8);

#pragma unroll
  for (int qt = 0; qt < 4; ++qt) {
    f32x4 accS[4] = {};
#pragma unroll
    for (int kk2 = 0; kk2 < 2; ++kk2)
#pragma unroll
      for (int j = 0; j < 4; ++j)
        accS[j] = __builtin_amdgcn_mfma_f32_16x16x32_bf16(qf[qt][kk2], kf[kk2][j],
                                                          accS[j], 0, 0, 0);
#pragma unroll
    for (int r = 0; r < 4; ++r) {
      float sv[4];
      float m = -1e30f;
#pragma unroll
      for (int j = 0; j < 4; ++j) { sv[j] = accS[j][r] * ATT_SCALE; m = fmaxf(m, sv[j]); }
#pragma unroll
      for (int off = 1; off < 16; off <<= 1) m = fmaxf(m, __shfl_xor(m, off, 64));
      float s = 0.f;
#pragma unroll
      for (int j = 0; j < 4; ++j) { sv[j] = __expf(sv[j] - m); s += sv[j]; }
#pragma unroll
      for (int off = 1; off < 16; off <<= 1) s += __shfl_xor(s, off, 64);
      float inv = 1.0f / s;
      int ql = kq * 4 + r;
#pragma unroll
      for (int j = 0; j < 4; ++j)
        Pw[ql * 72 + j * 16 + l16] = __float2bfloat16(sv[j] * inv);
    }
    __asm volatile("s_waitcnt lgkmcnt(0)" ::: "memory");

    f32x4 accO[4] = {};
#pragma unroll
    for (int kk2 = 0; kk2 < 2; ++kk2) {
      bf16x8 a = *(const bf16x8*)((const short*)Pw + l16 * 72 + kk2 * 32 + kq * 8);
#pragma unroll
      for (int j = 0; j < 4; ++j)
        accO[j] = __builtin_amdgcn_mfma_f32_16x16x32_bf16(a, vf[kk2][j], accO[j], 0, 0, 0);
    }
    __asm volatile("s_waitcnt lgkmcnt(0)" ::: "memory");

#pragma unroll
    for (int r = 0; r < 4; ++r) {
      int q = qt * 16 + kq * 4 + r;
      float mk = mask[b * SEQ + q] ? 1.0f : 0.0f;
#pragma unroll
      for (int j = 0; j < 4; ++j)
        Qw[base + q * DHD + j * 16 + l16] = __float2bfloat16(accO[j][r] * mk);
    }
  }
}

// ---------------------------------------------------------------------------
// Kernel 3: O projection + gated residual, same pipelined core.
// Hb(bf16) updated IN-PLACE: Hb = Hb + mask[m]*(O @ Wo^T).
// ---------------------------------------------------------------------------
__global__ void __launch_bounds__(512, 2)
gemm_o(const __hip_bfloat16* __restrict__ Ow,   // [B,H,seq,dh]
       const __hip_bfloat16* __restrict__ WoB,  // bf16 [1024][1024]
       const int* __restrict__ mask,
       __hip_bfloat16* Hb) {                    // residual in/out
  __shared__ __align__(16) char LdsA[2][BM * BKT * 2];
  __shared__ __align__(16) char LdsB[2][BN * BKT * 2];
  const int tid = threadIdx.x;
  const int lane = tid & 63, wave = tid >> 6;
  const int l16 = lane & 15, kq = lane >> 4;
  const int wr = wave >> 2, wc = wave & 3;
  const int m0 = blockIdx.x * BM, n0 = blockIdx.y * BN;
  const int wub = wave * 1024;
  const int srow = tid >> 3;
  const int scol8 = (((tid >> 3) & 7) ^ (tid & 7)) << 3;
  // A source: token t = m0 + q*64 + srow -> b = (m0>>6)+q, s = srow;
  // col f = jt*64 + scol8 -> h = jt, dh = scol8 (BKT == DHD == 64).
  const size_t ao_thr = ((size_t)(m0 >> 6) << 16) + (srow << 6) + scol8;
  const size_t b_thr = (size_t)(n0 + srow) * D_DIM + scol8;
  const int colsw0 = (kq * 16) ^ ((l16 & 7) << 4);
  const int colsw1 = (64 + kq * 16) ^ ((l16 & 7) << 4);
  const int aoff = (wr * 128 + l16) * 128;
  const int boff = (wc * 64 + l16) * 128;

  f32x4 acc[8][4] = {};
  bf16x8 af[4][2], bfr[4][2];

#define STG_A(BUF, JT, Q)                                                      \
  cp16(Ow + ao_thr + ((size_t)(Q) << 16) + ((size_t)(JT) << 12),               \
       LdsA[BUF] + (Q) * 8192 + wub)
#define STG_B(BUF, JT, Q)                                                      \
  cp16(WoB + b_thr + (size_t)(Q) * (64 * D_DIM) + (JT) * BKT,                  \
       LdsB[BUF] + (Q) * 8192 + wub)

  GEMM_PIPELINE();

#undef STG_A
#undef STG_B

#pragma unroll
  for (int i = 0; i < 8; ++i) {
#pragma unroll
    for (int r = 0; r < 4; ++r) {
      int gm = m0 + wr * 128 + i * 16 + kq * 4 + r;
      float mk = mask[gm] ? 1.0f : 0.0f;
#pragma unroll
      for (int jf = 0; jf < 4; ++jf) {
        int gn = n0 + wc * 64 + jf * 16 + l16;
        size_t idx = (size_t)gm * D_DIM + gn;
        Hb[idx] = __float2bfloat16(__bfloat162float(Hb[idx]) + mk * acc[i][jf][r]);
      }
    }
  }
}

// ---------------------------------------------------------------------------
// Kernel 4: LayerNorm over D=1024, bf16 in / fp32 out (unchanged).
// ---------------------------------------------------------------------------
__global__ void ln_bf(const __hip_bfloat16* __restrict__ Hf,
                      const float* __restrict__ gamma,
                      const float* __restrict__ beta,
                      float* __restrict__ out) {
  __shared__ float red[4];
  const int row = blockIdx.x, tid = threadIdx.x;
  const int wave = tid >> 6, lane = tid & 63;
  const size_t boff = (size_t)row * D_DIM + tid * 8;

  bf16x8 v = *(const bf16x8*)((const short*)Hf + boff);
  float f[8], s = 0.f, ss = 0.f;
#pragma unroll
  for (int k = 0; k < 8; ++k) { f[k] = bf2f(v[k]); s += f[k]; ss += f[k] * f[k]; }
#pragma unroll
  for (int off = 1; off < 64; off <<= 1) {
    s += __shfl_xor(s, off, 64);
    ss += __shfl_xor(ss, off, 64);
  }
  if (lane == 0) { red[wave * 2] = s; red[wave * 2 + 1] = ss; }
  __syncthreads();
  s = red[0] + red[2];
  ss = red[1] + red[3];
  const float mu = s * (1.0f / D_DIM);
  const float var = ss * (1.0f / D_DIM) - mu * mu;
  const float rs = rsqrtf(var + LN_EPS);

  float4 g0 = ((const float4*)(gamma + tid * 8))[0];
  float4 g1 = ((const float4*)(gamma + tid * 8))[1];
  float4 b0 = ((const float4*)(beta + tid * 8))[0];
  float4 b1 = ((const float4*)(beta + tid * 8))[1];
  float g[8] = {g0.x, g0.y, g0.z, g0.w, g1.x, g1.y, g1.z, g1.w};
  float bb[8] = {b0.x, b0.y, b0.z, b0.w, b1.x, b1.y, b1.z, b1.w};
  float o[8];
#pragma unroll
  for (int k = 0; k < 8; ++k)
    o[k] = (f[k] - mu) * rs * g[k] + bb[k];
  ((float4*)(out + boff))[0] = make_float4(o[0], o[1], o[2], o[3]);
  ((float4*)(out + boff))[1] = make_float4(o[4], o[5], o[6], o[7]);
}

// ---------------------------------------------------------------------------
extern "C" void kernel_launch(void* const* d_in, const int* in_sizes, int n_in,
                              void* d_out, int out_size, void* d_ws, size_t ws_size,
                              hipStream_t stream) {
  const float* hidden = (const float*)d_in[0];
  const int* mask = (const int*)d_in[1];
  const float* Wq = (const float*)d_in[2];
  const float* Wk = (const float*)d_in[3];
  const float* Wv = (const float*)d_in[4];
  const float* Wo = (const float*)d_in[5];
  const float* gamma = (const float*)d_in[6];
  const float* beta = (const float*)d_in[7];
  float* out = (float*)d_out;

  const size_t SZ = (size_t)M_TOT * D_DIM;        // 16,777,216 elements
  __hip_bfloat16* Hb   = (__hip_bfloat16*)d_ws;   // bf16 hidden; in-place residual
  __hip_bfloat16* Kw   = Hb + SZ;
  __hip_bfloat16* Qw   = Hb + 2 * SZ;             // O written in-place by attn
  __hip_bfloat16* Vtw  = Hb + 3 * SZ;
  __hip_bfloat16* Wall = Hb + 4 * SZ;             // bf16 [4][1024][1024]

  conv_all<<<dim3(10240), 256, 0, stream>>>(Wq, Wk, Wv, Wo, hidden, Wall, Hb);
  gemm_qkv_bf<<<dim3(64, 4, 3), 512, 0, stream>>>(Hb, Wall, Qw, Kw, Vtw);
  attn_v2<<<dim3(1024), 256, 0, stream>>>(Qw, Kw, Vtw, mask);
  gemm_o<<<dim3(64, 4), 512, 0, stream>>>(Qw, Wall + 3 * D_DIM * D_DIM, mask, Hb);
  ln_bf<<<dim3(16384), 128, 0, stream>>>(Hb, gamma, beta, out);
}